// Round 1
// baseline (729.554 us; speedup 1.0000x reference)
//
#include <hip/hip_runtime.h>

typedef __attribute__((ext_vector_type(8))) __bf16 bf16x8;
typedef __attribute__((ext_vector_type(4))) float f32x4;
typedef __attribute__((ext_vector_type(8))) unsigned short u16x8;

#define TM 128
#define TN 128
#define BK 64

// ---------- fp32 -> bf16 (RNE) ----------
__device__ inline unsigned short f2bf(float f) {
    unsigned int u = __float_as_uint(f);
    u += 0x7FFFu + ((u >> 16) & 1u);
    return (unsigned short)(u >> 16);
}

// ---------- scatter-add COO into dense fp32 ----------
__global__ void scatter_kernel(const float* __restrict__ vals,
                               const int* __restrict__ rows,
                               const int* __restrict__ cols,
                               float* __restrict__ Df,
                               int nnz, int in_f) {
    int i = blockIdx.x * blockDim.x + threadIdx.x;
    if (i < nnz) {
        atomicAdd(&Df[(size_t)rows[i] * in_f + cols[i]], vals[i]);
    }
}

// ---------- fp32 -> bf16 bulk convert, 8 elems/thread ----------
__global__ void cvt_kernel(const float* __restrict__ src,
                           unsigned short* __restrict__ dst,
                           long n) {
    long i = ((long)blockIdx.x * blockDim.x + threadIdx.x) * 8;
    if (i + 8 <= n) {
        f32x4 a = *(const f32x4*)(src + i);
        f32x4 b = *(const f32x4*)(src + i + 4);
        u16x8 o;
        o[0] = f2bf(a[0]); o[1] = f2bf(a[1]); o[2] = f2bf(a[2]); o[3] = f2bf(a[3]);
        o[4] = f2bf(b[0]); o[5] = f2bf(b[1]); o[6] = f2bf(b[2]); o[7] = f2bf(b[3]);
        *(u16x8*)(dst + i) = o;
    }
}

// ---------- bf16 NT GEMM: C[M,N] = A[M,K] * B[N,K]^T + bias, fp32 out ----------
// 128x128 tile, BK=64, 256 threads (4 waves, each 64x64), global_load_lds width=16.
__global__ __launch_bounds__(256) void gemm_bt_bias(
    const unsigned short* __restrict__ A,   // bf16 bits [M,K]
    const unsigned short* __restrict__ B,   // bf16 bits [N,K] (weight)
    const float* __restrict__ bias,         // [N]
    float* __restrict__ C,                  // [M,N]
    int M, int N, int K)
{
    __shared__ unsigned short sA[TM * BK];
    __shared__ unsigned short sB[TN * BK];

    const int tid  = threadIdx.x;
    const int lane = tid & 63;
    const int wave = tid >> 6;
    const int wm = (wave >> 1) * 64;   // wave row offset within tile
    const int wn = (wave & 1) * 64;    // wave col offset within tile
    const int bm = blockIdx.y * TM;
    const int bn = blockIdx.x * TN;

    const int quad = lane >> 4;
    const int mrow = lane & 15;

    f32x4 acc[4][4];
    #pragma unroll
    for (int a_ = 0; a_ < 4; ++a_)
        #pragma unroll
        for (int b_ = 0; b_ < 4; ++b_)
            acc[a_][b_] = (f32x4){0.f, 0.f, 0.f, 0.f};

    for (int k0 = 0; k0 < K; k0 += BK) {
        // ---- stage 128x64 bf16 A-tile and B-tile via global_load_lds (16B/lane) ----
        // chunk c = tid + i*256; row = c>>3 (0..127), kchunk = c&7 (8 bf16 each).
        // LDS dest: wave-uniform base + lane*16 (HW rule) == chunk*16 contiguous.
        #pragma unroll
        for (int i = 0; i < 4; ++i) {
            int c   = tid + i * 256;
            int row = c >> 3;
            int kc  = c & 7;
            const unsigned short* ga = A + (size_t)(bm + row) * K + k0 + kc * 8;
            const unsigned short* gb = B + (size_t)(bn + row) * K + k0 + kc * 8;
            unsigned short* la = sA + (size_t)(wave * 64 + i * 256) * 8;
            unsigned short* lb = sB + (size_t)(wave * 64 + i * 256) * 8;
            __builtin_amdgcn_global_load_lds(
                (const __attribute__((address_space(1))) void*)ga,
                (__attribute__((address_space(3))) void*)la, 16, 0, 0);
            __builtin_amdgcn_global_load_lds(
                (const __attribute__((address_space(1))) void*)gb,
                (__attribute__((address_space(3))) void*)lb, 16, 0, 0);
        }
        __syncthreads();   // compiler drains vmcnt before barrier

        // ---- 2 K-steps of 32, 16 MFMA each ----
        #pragma unroll
        for (int ks = 0; ks < 2; ++ks) {
            bf16x8 af[4], bfr[4];
            #pragma unroll
            for (int t = 0; t < 4; ++t) {
                af[t]  = *(const bf16x8*)(sA + (wm + t * 16 + mrow) * BK + ks * 32 + quad * 8);
                bfr[t] = *(const bf16x8*)(sB + (wn + t * 16 + mrow) * BK + ks * 32 + quad * 8);
            }
            #pragma unroll
            for (int tm_ = 0; tm_ < 4; ++tm_)
                #pragma unroll
                for (int tn_ = 0; tn_ < 4; ++tn_)
                    acc[tm_][tn_] = __builtin_amdgcn_mfma_f32_16x16x32_bf16(
                        af[tm_], bfr[tn_], acc[tm_][tn_], 0, 0, 0);
        }
        __syncthreads();
    }

    // ---- epilogue: C/D layout col=lane&15, row=quad*4+r; add bias, store fp32 ----
    #pragma unroll
    for (int tn_ = 0; tn_ < 4; ++tn_) {
        int col = bn + wn + tn_ * 16 + mrow;
        float bv = bias[col];
        #pragma unroll
        for (int tm_ = 0; tm_ < 4; ++tm_) {
            int row0 = bm + wm + tm_ * 16 + quad * 4;
            #pragma unroll
            for (int r = 0; r < 4; ++r) {
                C[(size_t)(row0 + r) * N + col] = acc[tm_][tn_][r] + bv;
            }
        }
    }
}

extern "C" void kernel_launch(void* const* d_in, const int* in_sizes, int n_in,
                              void* d_out, int out_size, void* d_ws, size_t ws_size,
                              hipStream_t stream) {
    const float* vals   = (const float*)d_in[0];
    const int*   rows   = (const int*)d_in[1];
    const int*   cols   = (const int*)d_in[2];
    const float* weight = (const float*)d_in[3];  // [OUT, IN] row-major
    const float* bias   = (const float*)d_in[4];

    const int NNZ = in_sizes[0];
    const int OUT = in_sizes[4];
    const int IN  = in_sizes[3] / OUT;
    const int M   = out_size / OUT;     // n_rows

    // workspace layout: Df fp32 [M,IN] | Ab bf16 [M,IN] | Wb bf16 [OUT,IN]
    float*          Df = (float*)d_ws;
    size_t dfBytes = (size_t)M * IN * sizeof(float);
    unsigned short* Ab = (unsigned short*)((char*)d_ws + dfBytes);
    unsigned short* Wb = (unsigned short*)((char*)d_ws + dfBytes + (size_t)M * IN * 2);

    // 1) zero dense
    hipMemsetAsync(Df, 0, dfBytes, stream);

    // 2) scatter-add (COO duplicates accumulate)
    scatter_kernel<<<(NNZ + 255) / 256, 256, 0, stream>>>(vals, rows, cols, Df, NNZ, IN);

    // 3) convert dense + weight to bf16
    {
        long nD = (long)M * IN;
        long nW = (long)OUT * IN;
        cvt_kernel<<<(int)((nD / 8 + 255) / 256), 256, 0, stream>>>(Df, Ab, nD);
        cvt_kernel<<<(int)((nW / 8 + 255) / 256), 256, 0, stream>>>(weight, Wb, nW);
    }

    // 4) GEMM + bias
    dim3 grid(OUT / TN, M / TM);   // 32 x 64 = 2048 blocks
    gemm_bt_bias<<<grid, 256, 0, stream>>>(Ab, Wb, bias, (float*)d_out, M, OUT, IN);
}

// Round 2
// 686.130 us; speedup vs baseline: 1.0633x; 1.0633x over previous
//
#include <hip/hip_runtime.h>

typedef __attribute__((ext_vector_type(8))) __bf16 bf16x8;
typedef __attribute__((ext_vector_type(4))) float f32x4;
typedef __attribute__((ext_vector_type(8))) unsigned short u16x8;

#define TM 128
#define TN 128
#define BK 64

// ---------- fp32 -> bf16 (RNE) ----------
__device__ inline unsigned short f2bf(float f) {
    unsigned int u = __float_as_uint(f);
    u += 0x7FFFu + ((u >> 16) & 1u);
    return (unsigned short)(u >> 16);
}

// ---------- scatter-add COO into dense fp32 ----------
__global__ __launch_bounds__(256) void scatter_kernel(
        const float* __restrict__ vals,
        const int* __restrict__ rows,
        const int* __restrict__ cols,
        float* __restrict__ Df,
        int nnz, int in_f) {
    int i = blockIdx.x * blockDim.x + threadIdx.x;
    if (i < nnz) {
        atomicAdd(&Df[(size_t)rows[i] * in_f + cols[i]], vals[i]);
    }
}

// ---------- fp32 -> bf16 bulk convert, 8 elems/thread ----------
__global__ __launch_bounds__(256) void cvt_kernel(
        const float* __restrict__ src,
        unsigned short* __restrict__ dst,
        long n) {
    long i = ((long)blockIdx.x * blockDim.x + threadIdx.x) * 8;
    if (i + 8 <= n) {
        f32x4 a = *(const f32x4*)(src + i);
        f32x4 b = *(const f32x4*)(src + i + 4);
        u16x8 o;
        o[0] = f2bf(a[0]); o[1] = f2bf(a[1]); o[2] = f2bf(a[2]); o[3] = f2bf(a[3]);
        o[4] = f2bf(b[0]); o[5] = f2bf(b[1]); o[6] = f2bf(b[2]); o[7] = f2bf(b[3]);
        *(u16x8*)(dst + i) = o;
    }
}

// ---------- bf16 NT GEMM: C[M,N] = A[M,K] * B[N,K]^T + bias, fp32 out ----------
// 128x128 tile, BK=64, 256 threads (4 waves, each 64x64).
// LDS layout XOR-swizzled: global chunk (row, kc) lives at LDS chunk
// (row, kc ^ (row&7)).  Kills the row-cancellation 16-way bank conflict of
// the plain row-major [128][64] layout (R1: 1.0e8 SQ_LDS_BANK_CONFLICT).
__global__ __launch_bounds__(256) void gemm_bt_bias(
    const unsigned short* __restrict__ A,   // bf16 bits [M,K]
    const unsigned short* __restrict__ B,   // bf16 bits [N,K] (weight)
    const float* __restrict__ bias,         // [N]
    float* __restrict__ C,                  // [M,N]
    int M, int N, int K)
{
    __shared__ unsigned short sA[TM * BK];
    __shared__ unsigned short sB[TN * BK];

    const int tid  = threadIdx.x;
    const int lane = tid & 63;
    const int wave = tid >> 6;
    const int wm = (wave >> 1) * 64;   // wave row offset within tile
    const int wn = (wave & 1) * 64;    // wave col offset within tile
    const int bm = blockIdx.y * TM;
    const int bn = blockIdx.x * TN;

    const int quad = lane >> 4;
    const int mrow = lane & 15;
    const int sw   = mrow & 7;         // row-dependent XOR for fragment reads

    // staging-side swizzle: chunk c -> global (row = c>>3, kc = (c&7) ^ (row&7))
    // (precompute per-iteration below; global coalescing unchanged: permutation
    //  stays within each 128B row segment)

    f32x4 acc[4][4];
    #pragma unroll
    for (int a_ = 0; a_ < 4; ++a_)
        #pragma unroll
        for (int b_ = 0; b_ < 4; ++b_)
            acc[a_][b_] = (f32x4){0.f, 0.f, 0.f, 0.f};

    for (int k0 = 0; k0 < K; k0 += BK) {
        #pragma unroll
        for (int i = 0; i < 4; ++i) {
            int c   = tid + i * 256;
            int row = c >> 3;
            int kc  = (c & 7) ^ (row & 7);          // swizzled source chunk
            const unsigned short* ga = A + (size_t)(bm + row) * K + k0 + kc * 8;
            const unsigned short* gb = B + (size_t)(bn + row) * K + k0 + kc * 8;
            unsigned short* la = sA + (size_t)(wave * 64 + i * 256) * 8;
            unsigned short* lb = sB + (size_t)(wave * 64 + i * 256) * 8;
            __builtin_amdgcn_global_load_lds(
                (const __attribute__((address_space(1))) void*)ga,
                (__attribute__((address_space(3))) void*)la, 16, 0, 0);
            __builtin_amdgcn_global_load_lds(
                (const __attribute__((address_space(1))) void*)gb,
                (__attribute__((address_space(3))) void*)lb, 16, 0, 0);
        }
        __syncthreads();

        // ---- 2 K-steps of 32, 16 MFMA each ----
        #pragma unroll
        for (int ks = 0; ks < 2; ++ks) {
            const int kcs = (ks * 4 + quad) ^ sw;   // swizzled LDS chunk index
            bf16x8 af[4], bfr[4];
            #pragma unroll
            for (int t = 0; t < 4; ++t) {
                af[t]  = *(const bf16x8*)(sA + (wm + t * 16 + mrow) * BK + kcs * 8);
                bfr[t] = *(const bf16x8*)(sB + (wn + t * 16 + mrow) * BK + kcs * 8);
            }
            #pragma unroll
            for (int tm_ = 0; tm_ < 4; ++tm_)
                #pragma unroll
                for (int tn_ = 0; tn_ < 4; ++tn_)
                    acc[tm_][tn_] = __builtin_amdgcn_mfma_f32_16x16x32_bf16(
                        af[tm_], bfr[tn_], acc[tm_][tn_], 0, 0, 0);
        }
        __syncthreads();
    }

    // ---- epilogue: C/D layout col=lane&15, row=quad*4+r; add bias, store fp32 ----
    #pragma unroll
    for (int tn_ = 0; tn_ < 4; ++tn_) {
        int col = bn + wn + tn_ * 16 + mrow;
        float bv = bias[col];
        #pragma unroll
        for (int tm_ = 0; tm_ < 4; ++tm_) {
            int row0 = bm + wm + tm_ * 16 + quad * 4;
            #pragma unroll
            for (int r = 0; r < 4; ++r) {
                C[(size_t)(row0 + r) * N + col] = acc[tm_][tn_][r] + bv;
            }
        }
    }
}

extern "C" void kernel_launch(void* const* d_in, const int* in_sizes, int n_in,
                              void* d_out, int out_size, void* d_ws, size_t ws_size,
                              hipStream_t stream) {
    const float* vals   = (const float*)d_in[0];
    const int*   rows   = (const int*)d_in[1];
    const int*   cols   = (const int*)d_in[2];
    const float* weight = (const float*)d_in[3];  // [OUT, IN] row-major
    const float* bias   = (const float*)d_in[4];

    const int NNZ = in_sizes[0];
    const int OUT = in_sizes[4];
    const int IN  = in_sizes[3] / OUT;
    const int M   = out_size / OUT;     // n_rows

    // workspace layout: Df fp32 [M,IN] | Ab bf16 [M,IN] | Wb bf16 [OUT,IN]
    float*          Df = (float*)d_ws;
    size_t dfBytes = (size_t)M * IN * sizeof(float);
    unsigned short* Ab = (unsigned short*)((char*)d_ws + dfBytes);
    unsigned short* Wb = (unsigned short*)((char*)d_ws + dfBytes + (size_t)M * IN * 2);

    // 1) zero dense
    hipMemsetAsync(Df, 0, dfBytes, stream);

    // 2) scatter-add (COO duplicates accumulate)
    scatter_kernel<<<(NNZ + 255) / 256, 256, 0, stream>>>(vals, rows, cols, Df, NNZ, IN);

    // 3) convert dense + weight to bf16
    {
        long nD = (long)M * IN;
        long nW = (long)OUT * IN;
        cvt_kernel<<<(int)((nD / 8 + 255) / 256), 256, 0, stream>>>(Df, Ab, nD);
        cvt_kernel<<<(int)((nW / 8 + 255) / 256), 256, 0, stream>>>(weight, Wb, nW);
    }

    // 4) GEMM + bias
    dim3 grid(OUT / TN, M / TM);   // 32 x 64 = 2048 blocks
    gemm_bt_bias<<<grid, 256, 0, stream>>>(Ab, Wb, bias, (float*)d_out, M, OUT, IN);
}

// Round 3
// 553.692 us; speedup vs baseline: 1.3176x; 1.2392x over previous
//
#include <hip/hip_runtime.h>

typedef __attribute__((ext_vector_type(8)))  __bf16 bf16x8;
typedef __attribute__((ext_vector_type(16))) float  f32x16;
typedef __attribute__((ext_vector_type(4)))  float  f32x4;
typedef __attribute__((ext_vector_type(8)))  unsigned short u16x8;

#define TM 128
#define TN 128
#define BK 64

// ---------- fp32 -> bf16 (RNE) ----------
__device__ inline unsigned short f2bf(float f) {
    unsigned int u = __float_as_uint(f);
    u += 0x7FFFu + ((u >> 16) & 1u);
    return (unsigned short)(u >> 16);
}

// ---------- scatter-add COO directly into bf16 dense via 32-bit CAS ----------
// Region is 64MB (vs 128MB fp32) and removes the whole 192MB cvt-A pass.
// Duplicate (row,col) indices accumulate with per-add bf16 rounding; dup count
// ~38K pairs, error contribution << bf16 GEMM rounding (analyzed R2->R3).
__global__ __launch_bounds__(256) void scatter_bf16(
        const float* __restrict__ vals,
        const int* __restrict__ rows,
        const int* __restrict__ cols,
        unsigned short* __restrict__ Ab,
        int nnz, int in_f) {
    int i = blockIdx.x * blockDim.x + threadIdx.x;
    if (i >= nnz) return;
    float v = vals[i];
    size_t idx = (size_t)rows[i] * in_f + cols[i];
    unsigned int* word = (unsigned int*)(Ab + (idx & ~(size_t)1));
    unsigned int sh = (unsigned int)(idx & 1) * 16u;
    unsigned int old = *word, assumed;
    do {
        assumed = old;
        unsigned int cur = (assumed >> sh) & 0xFFFFu;
        float f = __uint_as_float(cur << 16) + v;
        unsigned int nb = f2bf(f);
        unsigned int repl = (assumed & ~(0xFFFFu << sh)) | (nb << sh);
        old = atomicCAS(word, assumed, repl);
    } while (old != assumed);
}

// ---------- fp32 -> bf16 bulk convert (weight), 8 elems/thread ----------
__global__ __launch_bounds__(256) void cvt_kernel(
        const float* __restrict__ src,
        unsigned short* __restrict__ dst,
        long n) {
    long i = ((long)blockIdx.x * blockDim.x + threadIdx.x) * 8;
    if (i + 8 <= n) {
        f32x4 a = *(const f32x4*)(src + i);
        f32x4 b = *(const f32x4*)(src + i + 4);
        u16x8 o;
        o[0] = f2bf(a[0]); o[1] = f2bf(a[1]); o[2] = f2bf(a[2]); o[3] = f2bf(a[3]);
        o[4] = f2bf(b[0]); o[5] = f2bf(b[1]); o[6] = f2bf(b[2]); o[7] = f2bf(b[3]);
        *(u16x8*)(dst + i) = o;
    }
}

// ---------- bf16 NT GEMM: C[M,N] = A[M,K] * B[N,K]^T + bias, fp32 out ----------
// 128x128 tile, BK=64, 256 threads (4 waves, each 64x64 as 2x2 of 32x32 MFMA).
// 32x32x16 MFMA: same LDS bytes/FLOP as 16x16x32 but 17% less MFMA-pipe time
// (m06: 2382 vs 2075 TF; 8.07 vs 4.85 cyc/inst for 2x the FLOP).
// XOR swizzle (row&7) keeps SQ_LDS_BANK_CONFLICT at 0: per 4-bank group,
// exactly 8 lanes (4 per k-half) -> 8 word-accesses/bank = balanced.
__global__ __launch_bounds__(256) void gemm_bt_bias(
    const unsigned short* __restrict__ A,   // bf16 bits [M,K]
    const unsigned short* __restrict__ B,   // bf16 bits [N,K] (weight)
    const float* __restrict__ bias,         // [N]
    float* __restrict__ C,                  // [M,N]
    int M, int N, int K)
{
    __shared__ unsigned short sA[TM * BK];
    __shared__ unsigned short sB[TN * BK];

    const int tid  = threadIdx.x;
    const int lane = tid & 63;
    const int wave = tid >> 6;
    const int wm = (wave >> 1) * 64;   // wave row offset within tile
    const int wn = (wave & 1) * 64;    // wave col offset within tile
    const int bm = blockIdx.y * TM;
    const int bn = blockIdx.x * TN;

    const int m32 = lane & 31;         // row/col within 32x32 MFMA
    const int h   = lane >> 5;         // k-half selector
    const int sw  = m32 & 7;           // XOR swizzle key

    f32x16 acc[2][2];
    #pragma unroll
    for (int t = 0; t < 2; ++t)
        #pragma unroll
        for (int u = 0; u < 2; ++u)
            #pragma unroll
            for (int r = 0; r < 16; ++r)
                acc[t][u][r] = 0.f;

    for (int k0 = 0; k0 < K; k0 += BK) {
        // ---- stage 128x64 bf16 A/B tiles via global_load_lds (16B/lane) ----
        // LDS chunk c holds global (row=c>>3, kc=(c&7)^(row&7)) — XOR swizzle.
        #pragma unroll
        for (int i = 0; i < 4; ++i) {
            int c   = tid + i * 256;
            int row = c >> 3;
            int kc  = (c & 7) ^ (row & 7);
            const unsigned short* ga = A + (size_t)(bm + row) * K + k0 + kc * 8;
            const unsigned short* gb = B + (size_t)(bn + row) * K + k0 + kc * 8;
            unsigned short* la = sA + (size_t)(wave * 64 + i * 256) * 8;
            unsigned short* lb = sB + (size_t)(wave * 64 + i * 256) * 8;
            __builtin_amdgcn_global_load_lds(
                (const __attribute__((address_space(1))) void*)ga,
                (__attribute__((address_space(3))) void*)la, 16, 0, 0);
            __builtin_amdgcn_global_load_lds(
                (const __attribute__((address_space(1))) void*)gb,
                (__attribute__((address_space(3))) void*)lb, 16, 0, 0);
        }
        __syncthreads();

        // ---- 4 K-chunks of 16; 4 ds_read_b128 + 4 MFMA each ----
        #pragma unroll
        for (int kc = 0; kc < 4; ++kc) {
            const int cs = (kc * 2 + h) ^ sw;      // swizzled LDS chunk
            bf16x8 a0 = *(const bf16x8*)(sA + (wm      + m32) * BK + cs * 8);
            bf16x8 a1 = *(const bf16x8*)(sA + (wm + 32 + m32) * BK + cs * 8);
            bf16x8 b0 = *(const bf16x8*)(sB + (wn      + m32) * BK + cs * 8);
            bf16x8 b1 = *(const bf16x8*)(sB + (wn + 32 + m32) * BK + cs * 8);
            acc[0][0] = __builtin_amdgcn_mfma_f32_32x32x16_bf16(a0, b0, acc[0][0], 0, 0, 0);
            acc[0][1] = __builtin_amdgcn_mfma_f32_32x32x16_bf16(a0, b1, acc[0][1], 0, 0, 0);
            acc[1][0] = __builtin_amdgcn_mfma_f32_32x32x16_bf16(a1, b0, acc[1][0], 0, 0, 0);
            acc[1][1] = __builtin_amdgcn_mfma_f32_32x32x16_bf16(a1, b1, acc[1][1], 0, 0, 0);
        }
        __syncthreads();
    }

    // ---- epilogue: C/D layout col=lane&31, row=(reg&3)+8*(reg>>2)+4*h ----
    #pragma unroll
    for (int u = 0; u < 2; ++u) {
        int col = bn + wn + u * 32 + m32;
        float bv = bias[col];
        #pragma unroll
        for (int t = 0; t < 2; ++t) {
            int rbase = bm + wm + t * 32 + 4 * h;
            #pragma unroll
            for (int r = 0; r < 16; ++r) {
                int row = rbase + (r & 3) + 8 * (r >> 2);
                __builtin_nontemporal_store(acc[t][u][r] + bv,
                                            &C[(size_t)row * N + col]);
            }
        }
    }
}

extern "C" void kernel_launch(void* const* d_in, const int* in_sizes, int n_in,
                              void* d_out, int out_size, void* d_ws, size_t ws_size,
                              hipStream_t stream) {
    const float* vals   = (const float*)d_in[0];
    const int*   rows   = (const int*)d_in[1];
    const int*   cols   = (const int*)d_in[2];
    const float* weight = (const float*)d_in[3];  // [OUT, IN] row-major
    const float* bias   = (const float*)d_in[4];

    const int NNZ = in_sizes[0];
    const int OUT = in_sizes[4];
    const int IN  = in_sizes[3] / OUT;
    const int M   = out_size / OUT;     // n_rows

    // workspace layout: Ab bf16 [M,IN] | Wb bf16 [OUT,IN]
    unsigned short* Ab = (unsigned short*)d_ws;
    size_t abBytes = (size_t)M * IN * sizeof(unsigned short);
    unsigned short* Wb = (unsigned short*)((char*)d_ws + abBytes);

    // 1) zero bf16 dense (bf16 zero == 0x0000)
    hipMemsetAsync(Ab, 0, abBytes, stream);

    // 2) scatter-add COO directly into bf16 (CAS; duplicates accumulate)
    scatter_bf16<<<(NNZ + 255) / 256, 256, 0, stream>>>(vals, rows, cols, Ab, NNZ, IN);

    // 3) convert weight to bf16
    {
        long nW = (long)OUT * IN;
        cvt_kernel<<<(int)((nW / 8 + 255) / 256), 256, 0, stream>>>(weight, Wb, nW);
    }

    // 4) GEMM + bias
    dim3 grid(OUT / TN, M / TM);   // 32 x 64 = 2048 blocks
    gemm_bt_bias<<<grid, 256, 0, stream>>>(Ab, Wb, bias, (float*)d_out, M, OUT, IN);
}